// Round 6
// baseline (74.379 us; speedup 1.0000x reference)
//
#include <hip/hip_runtime.h>
#include <math.h>

// ---------------------------------------------------------------------------
// FullyQuantumRNN, round 17: double TLP — 32 lanes/batch, 2 blocks/CU.
// R16 post-mortem: packed fp32 neutral, and rocprof finally caught the kernel:
// VALUBusy 14.4%, Occupancy 18.3%, conflicts/HBM negligible -> latency-bound
// at 2 waves/SIMD (grid 256 = 1 block/CU). The fix is parallelism, not
// instruction count:
//  - 32 lanes per batch: phase 1 assigns ONE timestep per lane (per-lane work
//    halves: 6 v_cos, one Xb, one dot per row); phase 2's 16-slot DPP
//    butterfly runs duplicated in each 16-lane half (quad_perm / 
//    row_half_mirror / row_ror:8 are all 16-lane-row-local -> identical h0,h1
//    in both halves, zero extra ops).
//  - 512-thread blocks = 16 batches; grid = 512 = 2 blocks/CU; LDS ~52KB
//    (fits x2); __launch_bounds__(512,4) -> 4 waves/SIMD, 16 waves/CU.
//  - stage A/B/C redundancy doubles chip-wide but overlaps with the
//    co-resident block's compute phases.
// All validated algebra (product-tree stage B, packed gates, storage-frame
// GMASK/FMASK, folded-cos recurrence, f4c preload, DPP butterfly) verbatim.
// ---------------------------------------------------------------------------

using f32x2 = __attribute__((ext_vector_type(2))) float;
using f32x4 = __attribute__((ext_vector_type(4))) float;

// ---- compile-time permutation algebra (R1..R10-verified) ----
constexpr int cnot_ct(int idx, int c, int t) {
    return (idx & (1 << (4 - c))) ? (idx ^ (1 << (4 - t))) : idx;
}
constexpr int Pfwd_ct(int x, int r) {            // new[i] = old[Pfwd(i)]
    for (int w = 4; w >= 0; --w) x = cnot_ct(x, w, (w + r) % 5);
    return x;
}
constexpr int Pinv_ct(int x, int r) {
    for (int w = 0; w <= 4; ++w) x = cnot_ct(x, w, (w + r) % 5);
    return x;
}
static_assert(Pinv_ct(Pfwd_ct(13, 1), 1) == 13, "inv1");
static_assert(Pinv_ct(Pfwd_ct(22, 2), 2) == 22, "inv2");

// gate pair masks (storage-frame) and row-select functionals
constexpr int GMASK[10] = {16, 8, 4, 2, 1,
                           Pfwd_ct(16,1), Pfwd_ct(8,1), Pfwd_ct(4,1), Pfwd_ct(2,1), Pfwd_ct(1,1)};
constexpr int fmask_l1(int pb) {
    int f = 0;
    for (int b = 0; b < 5; ++b) if ((Pinv_ct(1 << b, 1) >> pb) & 1) f |= 1 << b;
    return f;
}
constexpr int FMASK[10] = {16, 8, 4, 2, 1,
                           fmask_l1(4), fmask_l1(3), fmask_l1(2), fmask_l1(1), fmask_l1(0)};
// expZ sign functionals on the storage index (final wires 3,4)
constexpr int cinv_ct(int x) { return Pinv_ct(Pinv_ct(x, 1), 2); }
constexpr int fmask_fin(int pb) {
    int f = 0;
    for (int b = 0; b < 5; ++b) if ((cinv_ct(1 << b) >> pb) & 1) f |= 1 << b;
    return f;
}
constexpr int SF3 = fmask_fin(1);
constexpr int SF4 = fmask_fin(0);

// each gate's pair must straddle its row-functional (one beta=0, one beta=1)
constexpr bool gates_straddle() {
    for (int g = 0; g < 10; ++g)
        if (!(__builtin_popcount(GMASK[g] & FMASK[g]) & 1)) return false;
    return true;
}
static_assert(gates_straddle(), "GMASK/FMASK straddle");

// phase-2 butterfly {1,2,7} spans 8-lane halves (R6-validated scheme)
constexpr unsigned span3_ct(int a, int b, int c) {
    unsigned m = 0;
    for (int i = 0; i < 8; ++i) {
        int v = ((i & 1) ? a : 0) ^ ((i & 2) ? b : 0) ^ ((i & 4) ? c : 0);
        m |= 1u << v;
    }
    return m;
}
static_assert(span3_ct(1, 2, 7) == 0xFFu, "butterfly {1,2,7} spans lanes 0..7");

__device__ __forceinline__ int pinv_rt(int x, int r) {
    #pragma unroll
    for (int w = 0; w < 5; ++w) {
        int cbit = 1 << (4 - w), tbit = 1 << (4 - ((w + r) % 5));
        if (x & cbit) x ^= tbit;
    }
    return x;
}

// ---- W = V^-1 rows, branchless ----
// W[0]={1/3,1/3,1/3}  W[1]={2/3,-1/3,-1/3}  W[2]={0,+s3,-s3}
__device__ __forceinline__ float Wsel(int r, int d) {
    float b, c;
    if (d == 0)      { b =  2.f / 3.f; c = 0.f; }
    else if (d == 1) { b = -1.f / 3.f; c =  0.57735026918962576f; }
    else             { b = -1.f / 3.f; c = -0.57735026918962576f; }
    return (r == 0) ? (1.f / 3.f) : ((r == 1) ? b : c);
}

// ---- static float4 component select (folds to a register at compile time) --
__device__ __forceinline__ float f4c(const float4& v, int c) {
    return (c == 0) ? v.x : ((c == 1) ? v.y : ((c == 2) ? v.z : v.w));
}

// ---- packed helpers ----
__device__ __forceinline__ f32x2 pkfma(f32x2 a, f32x2 b, f32x2 c) {
    return __builtin_elementwise_fma(a, b, c);
}
__device__ __forceinline__ f32x2 splat2(float v) { return (f32x2){v, v}; }

// ---- cross-lane xor via DPP (phase-2 recurrence; 16-lane-row local) ----
template<int CTRL> __device__ __forceinline__ float dppf(float x) {
    return __int_as_float(__builtin_amdgcn_mov_dpp(__float_as_int(x), CTRL, 0xF, 0xF, true));
}
template<int PL> __device__ __forceinline__ float mvf(float x) {
    if constexpr (PL == 1)      return dppf<0xB1>(x);    // quad_perm xor1
    else if constexpr (PL == 2) return dppf<0x4E>(x);    // quad_perm xor2
    else if constexpr (PL == 7) return dppf<0x141>(x);   // row_half_mirror = xor7
    else if constexpr (PL == 8) return dppf<0x128>(x);   // row_ror:8 = xor8
    else { static_assert(PL == 1 || PL == 2 || PL == 7 || PL == 8, "mask"); return x; }
}

// ---- full-state Ry in storage frame, PACKED {re,im}: mask m, functional F ----
template<int g>
__device__ __forceinline__ void gate_full2(f32x2 (&amp)[32], f32x2 cc, f32x2 ss) {
    constexpr int m = GMASK[g], F = FMASK[g];
    #pragma unroll
    for (int i = 0; i < 32; ++i) {
        if ((__builtin_popcount(i & F) & 1) == 0) {   // beta=0 member of pair
            const int j = i ^ m;                      // beta=1 (straddle assert)
            const f32x2 v0 = amp[i], v1 = amp[j];
            amp[i] = pkfma(cc, v0, -(ss * v1));       // c*v0 - s*v1 (re & im)
            amp[j] = pkfma(ss, v0,  cc * v1);         // s*v0 + c*v1
        }
    }
}

__global__ __launch_bounds__(512, 4) void qrnn_fused(
    const float* __restrict__ x_seq, const float* __restrict__ w_rec,
    const float* __restrict__ w_out, float* __restrict__ out, int B) {

    __shared__ __align__(16) float4 xs4[16 * 33];     // staged x, padded rows
    __shared__ __align__(16) float A2s[18 * 28];      // contracted A, padded
    __shared__ float CgS[10], SgS[10];                // cos/sin(theta_g/2)
    __shared__ float F0c[5], F0s[5];                  // cos/sin(phi0_w/2)
    __shared__ __align__(8) f32x2 E1cs[32];           // interleaved {cos,sin}
    __shared__ float RC[16];                          // readout coefs
    __shared__ __align__(16) float Cm_pool[16 * 18 * 36];   // Cm; aliases Qs/P1s
    float* const Qs  = Cm_pool;                       // [486] eval results
    float* const P1s = Cm_pool + 512;                 // [486] C1 partials

    const int tloc = threadIdx.x;
    const int grp  = tloc >> 5;                       // 0..15: batch in block
    const int l    = tloc & 31;                       // 0..31: lane in batch
    const int k    = l & 15;                          // phase-2 slot
    const int b0   = blockIdx.x * 16;
    const int b    = b0 + grp;

    // ---- stage x: one (t, batch) pair per thread, coalesced-ish ----
    {
        const int ts = tloc >> 4, lbs = tloc & 15;
        const int gidx = (ts * B + (b0 + lbs)) * 3;
        float4 v;
        v.x = x_seq[gidx]; v.y = x_seq[gidx + 1]; v.z = x_seq[gidx + 2]; v.w = 0.f;
        xs4[lbs * 33 + ts] = v;
    }

    // ---- stage A: all libm trig, distributed (depth ~2 calls) ----
    if (tloc < 10) {
        const float th = w_rec[(tloc / 5) * 15 + (tloc % 5) * 3 + 1];
        CgS[tloc] = cosf(0.5f * th);
        SgS[tloc] = sinf(0.5f * th);
    } else if (tloc >= 16 && tloc < 21) {             // per-qubit phi0/2
        const int w = tloc - 16;
        const float ph = 0.5f * w_rec[w * 3 + 0];
        F0c[w] = cosf(ph); F0s[w] = sinf(ph);
    } else if (tloc >= 64 && tloc < 96) {             // E1 = D_w0 * P1-frame D_phi1
        const int i = tloc - 64;
        const int j = pinv_rt(i, 1);
        float ang = 0.f;
        #pragma unroll
        for (int w = 0; w < 5; ++w) {
            ang += (((i >> (4 - w)) & 1) ? 0.5f : -0.5f) * w_rec[w * 3 + 2];
            ang += (((j >> (4 - w)) & 1) ? 0.5f : -0.5f) * w_rec[15 + w * 3 + 0];
        }
        E1cs[i] = (f32x2){cosf(ang), sinf(ang)};
    } else if (tloc >= 96 && tloc < 100) {            // readout gate coefs
        const int g = tloc - 96;                      // g = li*2 + w
        const int li = g >> 1, w = g & 1;
        const float phi = w_out[li * 6 + w * 3 + 0];
        const float the = w_out[li * 6 + w * 3 + 1];
        const float ome = w_out[li * 6 + w * 3 + 2];
        const float cs = cosf(0.5f * the), ss = sinf(0.5f * the);
        const float cp = cosf(0.5f * (phi + ome)), sp = sinf(0.5f * (phi + ome));
        const float cm = cosf(0.5f * (phi - ome)), sm = sinf(0.5f * (phi - ome));
        RC[g * 4 + 0] = cp * cs;
        RC[g * 4 + 1] = -sp * cs;
        RC[g * 4 + 2] = cm * ss;
        RC[g * 4 + 3] = sm * ss;
    }
    __syncthreads();

    // ---- stage B: per-thread full-state eval at exact combo angles ----
    if (tloc < 243) {
        const int dsel[5] = {tloc / 81, (tloc / 27) % 3, (tloc / 9) % 3,
                             (tloc / 3) % 3, tloc % 3};
        constexpr float S3v = 0.86602540378443865f;
        float Arw[5], Aiw[5], Brw[5], Biw[5];
        #pragma unroll
        for (int w = 0; w < 5; ++w) {
            const int d = dsel[w];
            const float fc = (d == 0) ? 1.f : 0.5f;
            const float fs = (d == 0) ? 0.f : ((d == 1) ? S3v : -S3v);
            const float c = CgS[w], s = SgS[w];
            const float t1 = fmaf(c, fc, -s * fs);   // c*fc - s*fs
            const float t2 = fmaf(c, fc,  s * fs);   // c*fc + s*fs
            const float t3 = fmaf(s, fc,  c * fs);   // s*fc + c*fs
            const float t4 = fmaf(c, fs, -s * fc);   // c*fs - s*fc
            Arw[w] =  F0c[w] * t1;  Aiw[w] = -F0s[w] * t2;
            Brw[w] =  F0c[w] * t3;  Biw[w] =  F0s[w] * t4;
        }
        f32x2 amp[32];
        amp[0] = (f32x2){Arw[0], Aiw[0]};
        amp[1] = (f32x2){Brw[0], Biw[0]};
        #pragma unroll
        for (int w = 1; w < 5; ++w) {
            const int n = 1 << w;
            #pragma unroll
            for (int m = n - 1; m >= 0; --m) {        // descending: in-place safe
                const float orr = amp[m].x, oii = amp[m].y;
                amp[2*m]   = (f32x2){fmaf(orr, Arw[w], -oii * Aiw[w]),
                                     fmaf(orr, Aiw[w],  oii * Arw[w])};
                amp[2*m+1] = (f32x2){fmaf(orr, Brw[w], -oii * Biw[w]),
                                     fmaf(orr, Biw[w],  oii * Brw[w])};
            }
        }
        // merged diagonal E1 (D_omega1 dropped: phase-blind)
        #pragma unroll
        for (int i = 0; i < 32; ++i) {
            const f32x2 e = E1cs[i];
            const f32x2 a = amp[i];
            amp[i] = (f32x2){a.x * e.x - a.y * e.y, a.x * e.y + a.y * e.x};
        }
        // layer 1 in storage frame, packed (GMASK/FMASK functionals)
        {
            const f32x2 c5 = splat2(CgS[5]), s5 = splat2(SgS[5]);
            const f32x2 c6 = splat2(CgS[6]), s6 = splat2(SgS[6]);
            const f32x2 c7 = splat2(CgS[7]), s7 = splat2(SgS[7]);
            const f32x2 c8 = splat2(CgS[8]), s8 = splat2(SgS[8]);
            const f32x2 c9 = splat2(CgS[9]), s9 = splat2(SgS[9]);
            gate_full2<5>(amp, c5, s5);
            gate_full2<6>(amp, c6, s6);
            gate_full2<7>(amp, c7, s7);
            gate_full2<8>(amp, c8, s8);
            gate_full2<9>(amp, c9, s9);
        }
        // expZ via SF3/SF4 sign functionals (R2-R8-validated)
        float q0 = 0.f, q1 = 0.f;
        #pragma unroll
        for (int i = 0; i < 32; ++i) {
            const f32x2 t = amp[i] * amp[i];          // v_pk_mul_f32
            const float p = t.x + t.y;
            q0 += (__builtin_popcount(i & SF3) & 1) ? -p : p;
            q1 += (__builtin_popcount(i & SF4) & 1) ? -p : p;
        }
        *(f32x2*)&Qs[tloc * 2] = (f32x2){q0, q1};
    }
    __syncthreads();

    // ---- stage C1: contract d3,d4 packed over j (Qs j-pairs adjacent) ----
    if (tloc < 243) {
        const int e = tloc;
        const int d012 = e / 9, pq = e % 9, pp = pq / 3, qq2 = pq % 3;
        f32x2 acc = (f32x2){0.f, 0.f};
        #pragma unroll
        for (int d3 = 0; d3 < 3; ++d3) {
            const float wp = Wsel(pp, d3);
            #pragma unroll
            for (int d4 = 0; d4 < 3; ++d4) {
                const float w = wp * Wsel(qq2, d4);
                const f32x2 qp = *(const f32x2*)&Qs[(d012 * 9 + d3 * 3 + d4) * 2];
                acc = pkfma(splat2(w), qp, acc);
            }
        }
        *(f32x2*)&P1s[(d012 * 9 + pq) * 2] = acc;
    }
    __syncthreads();

    // ---- stage C2: contract d0,d1,d2 packed over j -> A2s rows pq, 9+pq ----
    if (tloc < 243) {
        const int pq = tloc / 27, col = tloc % 27;
        const int a0 = col / 9, a1 = (col / 3) % 3, a2 = col % 3;
        f32x2 acc = (f32x2){0.f, 0.f};
        #pragma unroll
        for (int dd0 = 0; dd0 < 3; ++dd0) {
            const float w0 = Wsel(a0, dd0);
            #pragma unroll
            for (int dd1 = 0; dd1 < 3; ++dd1) {
                const float w01 = w0 * Wsel(a1, dd1);
                #pragma unroll
                for (int dd2 = 0; dd2 < 3; ++dd2) {
                    const float w = w01 * Wsel(a2, dd2);
                    const f32x2 pp = *(const f32x2*)
                        &P1s[((dd0 * 9 + dd1 * 3 + dd2) * 9 + pq) * 2];
                    acc = pkfma(splat2(w), pp, acc);
                }
            }
        }
        A2s[pq * 28 + col]       = acc.x;             // j=0 row
        A2s[(9 + pq) * 28 + col] = acc.y;             // j=1 row
    }
    if (tloc < 18) A2s[tloc * 28 + 27] = 0.f;
    __syncthreads();   // A2s ready; Qs/P1s dead -> Cm_pool reusable

    // ---- phase 1: one timestep per lane: C[t=l][row] = A-row . Xb ----
    constexpr float Kf = 0.15915494309189535f;   // 1/(2*pi)
    const f32x4* Ap = (const f32x4*)A2s;         // wave-uniform LDS broadcast
    f32x4 bA[7], bB[7];
    #pragma unroll
    for (int i = 0; i < 7; ++i) bA[i] = Ap[i];   // hoisted: lgkmcnt drains
    #pragma unroll
    for (int i = 0; i < 7; ++i) bB[i] = Ap[7 + i];   // under the Xb trig below

    f32x2 Xp[14];                                // packed even/odd basis pairs
    {
        float Xb[28];
        const float4 xv = xs4[grp * 33 + l];
        const float cx0 = __builtin_amdgcn_cosf(xv.x * Kf);
        const float sx0 = __builtin_amdgcn_cosf(fmaf(xv.x, Kf, -0.25f));
        const float cx1 = __builtin_amdgcn_cosf(xv.y * Kf);
        const float sx1 = __builtin_amdgcn_cosf(fmaf(xv.y, Kf, -0.25f));
        const float cx2 = __builtin_amdgcn_cosf(xv.z * Kf);
        const float sx2 = __builtin_amdgcn_cosf(fmaf(xv.z, Kf, -0.25f));
        Xb[0] = 1.f;  Xb[1] = cx2;       Xb[2] = sx2;
        Xb[3] = cx1;  Xb[4] = cx1 * cx2; Xb[5] = cx1 * sx2;
        Xb[6] = sx1;  Xb[7] = sx1 * cx2; Xb[8] = sx1 * sx2;
        #pragma unroll
        for (int i = 0; i < 9; ++i) { Xb[9 + i] = cx0 * Xb[i]; Xb[18 + i] = sx0 * Xb[i]; }
        Xb[27] = 0.f;
        #pragma unroll
        for (int j = 0; j < 14; ++j) Xp[j] = (f32x2){Xb[2 * j], Xb[2 * j + 1]};
    }
    {
        float* const Cmg = Cm_pool + grp * (18 * 36);
        #pragma unroll 1
        for (int r = 0; r < 18; r += 2) {
            {
                f32x2 A00 = {0.f,0.f}, A01 = {0.f,0.f};
                #pragma unroll
                for (int i = 0; i < 7; ++i) {
                    const f32x2 lo = __builtin_shufflevector(bA[i], bA[i], 0, 1);
                    const f32x2 hi = __builtin_shufflevector(bA[i], bA[i], 2, 3);
                    A00 = pkfma(lo, Xp[2*i],   A00);
                    A01 = pkfma(hi, Xp[2*i+1], A01);
                }
                const f32x2 S = A00 + A01;
                Cmg[r * 36 + l] = S.x + S.y;
                if (r < 16) {
                    #pragma unroll
                    for (int i = 0; i < 7; ++i) bA[i] = Ap[(r + 2) * 7 + i];
                }
            }
            {
                f32x2 A00 = {0.f,0.f}, A01 = {0.f,0.f};
                #pragma unroll
                for (int i = 0; i < 7; ++i) {
                    const f32x2 lo = __builtin_shufflevector(bB[i], bB[i], 0, 1);
                    const f32x2 hi = __builtin_shufflevector(bB[i], bB[i], 2, 3);
                    A00 = pkfma(lo, Xp[2*i],   A00);
                    A01 = pkfma(hi, Xp[2*i+1], A01);
                }
                const f32x2 S = A00 + A01;
                Cmg[(r + 1) * 36 + l] = S.x + S.y;
                if (r < 16) {
                    #pragma unroll
                    for (int i = 0; i < 7; ++i) bB[i] = Ap[(r + 3) * 7 + i];
                }
            }
        }
    }
    // Cm written/read within the same 32-lane group (same wave) -> no barrier

    // ---- phase 2: recurrence; slot k, duplicated across 16-lane halves ----
    const int jj = k >> 3;
    const int term = (k & 7) + 1;
    const int rowA = jj * 9 + term;
    const int rowB = (k == 8) ? 9 : 0;            // zero row eliminated (R15)
    const float cbf = (k == 0 || k == 8) ? 1.f : 0.f;
    const int p = term / 3, q = term % 3;
    const float4* CA4 = (const float4*)(Cm_pool + grp * (18 * 36) + rowA * 36);
    const float4* CB4 = (const float4*)(Cm_pool + grp * (18 * 36) + rowB * 36);

    float4 qa[8], qb[8];                          // 16 ds_read_b128
    #pragma unroll
    for (int i = 0; i < 8; ++i) { qa[i] = CA4[i]; qb[i] = CB4[i]; }
    #pragma unroll
    for (int i = 0; i < 8; ++i) {                 // CB := 0 unless k in {0,8}
        qb[i].x *= cbf; qb[i].y *= cbf; qb[i].z *= cbf; qb[i].w *= cbf;
    }

    const float Kfu = (p == 0) ? 0.f : Kf;       // cos(0)=1 for p==0 lanes
    const float bu  = (p == 2) ? -0.25f : 0.f;   // -0.25 rev = sin
    const float Kfv = (q == 0) ? 0.f : Kf;
    const float bv  = (q == 2) ? -0.25f : 0.f;

    float h0 = 0.f, h1 = 0.f;
    #pragma unroll
    for (int t = 0; t < 32; ++t) {
        const float u = __builtin_amdgcn_cosf(fmaf(h0, Kfu, bu));
        const float v = __builtin_amdgcn_cosf(fmaf(h1, Kfv, bv));
        float val = fmaf(f4c(qa[t >> 2], t & 3), u * v, f4c(qb[t >> 2], t & 3));
        val += mvf<1>(val);
        val += mvf<2>(val);
        val += mvf<7>(val);
        const float other = mvf<8>(val);
        h0 = (k & 8) ? other : val;
        h1 = (k & 8) ? val : other;
    }

    // ---- readout: precomputed coefs + HW h-trig (R10-validated) ----
    constexpr float K2 = 0.5f * 0.15915494309189535f;
    const float ch0 = __builtin_amdgcn_cosf(h0 * K2);
    const float sh0 = __builtin_amdgcn_cosf(fmaf(h0, K2, -0.25f));
    const float ch1 = __builtin_amdgcn_cosf(h1 * K2);
    const float sh1 = __builtin_amdgcn_cosf(fmaf(h1, K2, -0.25f));
    float vr0 = ch0 * ch1, vr1 = ch0 * sh1, vr2 = sh0 * ch1, vr3 = sh0 * sh1;
    float vi0 = 0.f, vi1 = 0.f, vi2 = 0.f, vi3 = 0.f;

    #pragma unroll
    for (int li = 0; li < 2; ++li) {
        #pragma unroll
        for (int w = 0; w < 2; ++w) {
            const int g = li * 2 + w;
            const float are = RC[g*4+0], aim = RC[g*4+1];
            const float bre = RC[g*4+2], bim = RC[g*4+3];
            #define AP2(r0, i0, r1, i1) do {                                  \
                float n0r = are*(r0) - aim*(i0) - bre*(r1) + bim*(i1);        \
                float n0i = are*(i0) + aim*(r0) - bre*(i1) - bim*(r1);        \
                float n1r = bre*(r0) + bim*(i0) + are*(r1) + aim*(i1);        \
                float n1i = bre*(i0) - bim*(r0) + are*(i1) - aim*(r1);        \
                r0 = n0r; i0 = n0i; r1 = n1r; i1 = n1i; } while (0)
            if (w == 0) { AP2(vr0, vi0, vr2, vi2); AP2(vr1, vi1, vr3, vi3); }
            else        { AP2(vr0, vi0, vr1, vi1); AP2(vr2, vi2, vr3, vi3); }
            #undef AP2
        }
        // CNOT(0,1) then CNOT(1,0): composed perm [0,2,3,1] (R1-verified)
        float tr1 = vr2, ti1 = vi2, tr2 = vr3, ti2 = vi3, tr3 = vr1, ti3 = vi1;
        vr1 = tr1; vi1 = ti1; vr2 = tr2; vi2 = ti2; vr3 = tr3; vi3 = ti3;
    }

    const float outv = (vr0 * vr0 + vi0 * vi0 + vr1 * vr1 + vi1 * vi1) -
                       (vr2 * vr2 + vi2 * vi2 + vr3 * vr3 + vi3 * vi3);
    if (l == 0) out[b] = outv;
}

extern "C" void kernel_launch(void* const* d_in, const int* in_sizes, int n_in,
                              void* d_out, int out_size, void* d_ws, size_t ws_size,
                              hipStream_t stream) {
    const float* x_seq = (const float*)d_in[0];
    const float* w_rec = (const float*)d_in[1];
    const float* w_out = (const float*)d_in[2];
    float* out = (float*)d_out;

    const int B = out_size;             // 8192 (T fixed at 32 by the bench)
    const int grid = B / 16;            // 512 blocks, 2/CU (LDS ~52KB)

    hipLaunchKernelGGL(qrnn_fused, dim3(grid), dim3(512), 0, stream,
                       x_seq, w_rec, w_out, out, B);
}

// Round 7
// 72.223 us; speedup vs baseline: 1.0298x; 1.0298x over previous
//
#include <hip/hip_runtime.h>
#include <math.h>

// ---------------------------------------------------------------------------
// FullyQuantumRNN, round 18: R13 setup amortization + R17 lane-split + 4 w/SIMD.
// R17 post-mortem: -TLP gain was real but bought by 2x chip-wide setup
// (512 blocks): +5.3us regression -> setup ~5us serial path per instance.
// R18 geometry: 1024-thread blocks, 32 batches/block, 32 lanes/batch,
// grid = 256 (1 block/CU):
//  - setup instantiated once per 32 batches (R13 redundancy level, 4 setup
//    waves/CU; threads 0..242 of waves 0..3);
//  - 16 waves/CU = 4 waves/SIMD (double R13) hide the compute-phase latency;
//  - phase 1: ONE timestep per lane (R17-validated halved per-lane path);
//  - phase 2: R17-validated duplicated 16-lane-half DPP butterfly.
// All stage algebra verbatim from R16/R17 (packed stage B product tree,
// packed C1/C2, storage-frame GMASK/FMASK, folded-cos recurrence, f4c
// preload, zero-row elimination).
// ---------------------------------------------------------------------------

using f32x2 = __attribute__((ext_vector_type(2))) float;
using f32x4 = __attribute__((ext_vector_type(4))) float;

// ---- compile-time permutation algebra (R1..R10-verified) ----
constexpr int cnot_ct(int idx, int c, int t) {
    return (idx & (1 << (4 - c))) ? (idx ^ (1 << (4 - t))) : idx;
}
constexpr int Pfwd_ct(int x, int r) {            // new[i] = old[Pfwd(i)]
    for (int w = 4; w >= 0; --w) x = cnot_ct(x, w, (w + r) % 5);
    return x;
}
constexpr int Pinv_ct(int x, int r) {
    for (int w = 0; w <= 4; ++w) x = cnot_ct(x, w, (w + r) % 5);
    return x;
}
static_assert(Pinv_ct(Pfwd_ct(13, 1), 1) == 13, "inv1");
static_assert(Pinv_ct(Pfwd_ct(22, 2), 2) == 22, "inv2");

// gate pair masks (storage-frame) and row-select functionals
constexpr int GMASK[10] = {16, 8, 4, 2, 1,
                           Pfwd_ct(16,1), Pfwd_ct(8,1), Pfwd_ct(4,1), Pfwd_ct(2,1), Pfwd_ct(1,1)};
constexpr int fmask_l1(int pb) {
    int f = 0;
    for (int b = 0; b < 5; ++b) if ((Pinv_ct(1 << b, 1) >> pb) & 1) f |= 1 << b;
    return f;
}
constexpr int FMASK[10] = {16, 8, 4, 2, 1,
                           fmask_l1(4), fmask_l1(3), fmask_l1(2), fmask_l1(1), fmask_l1(0)};
// expZ sign functionals on the storage index (final wires 3,4)
constexpr int cinv_ct(int x) { return Pinv_ct(Pinv_ct(x, 1), 2); }
constexpr int fmask_fin(int pb) {
    int f = 0;
    for (int b = 0; b < 5; ++b) if ((cinv_ct(1 << b) >> pb) & 1) f |= 1 << b;
    return f;
}
constexpr int SF3 = fmask_fin(1);
constexpr int SF4 = fmask_fin(0);

// each gate's pair must straddle its row-functional (one beta=0, one beta=1)
constexpr bool gates_straddle() {
    for (int g = 0; g < 10; ++g)
        if (!(__builtin_popcount(GMASK[g] & FMASK[g]) & 1)) return false;
    return true;
}
static_assert(gates_straddle(), "GMASK/FMASK straddle");

// phase-2 butterfly {1,2,7} spans 8-lane halves (R6-validated scheme)
constexpr unsigned span3_ct(int a, int b, int c) {
    unsigned m = 0;
    for (int i = 0; i < 8; ++i) {
        int v = ((i & 1) ? a : 0) ^ ((i & 2) ? b : 0) ^ ((i & 4) ? c : 0);
        m |= 1u << v;
    }
    return m;
}
static_assert(span3_ct(1, 2, 7) == 0xFFu, "butterfly {1,2,7} spans lanes 0..7");

__device__ __forceinline__ int pinv_rt(int x, int r) {
    #pragma unroll
    for (int w = 0; w < 5; ++w) {
        int cbit = 1 << (4 - w), tbit = 1 << (4 - ((w + r) % 5));
        if (x & cbit) x ^= tbit;
    }
    return x;
}

// ---- W = V^-1 rows, branchless ----
// W[0]={1/3,1/3,1/3}  W[1]={2/3,-1/3,-1/3}  W[2]={0,+s3,-s3}
__device__ __forceinline__ float Wsel(int r, int d) {
    float b, c;
    if (d == 0)      { b =  2.f / 3.f; c = 0.f; }
    else if (d == 1) { b = -1.f / 3.f; c =  0.57735026918962576f; }
    else             { b = -1.f / 3.f; c = -0.57735026918962576f; }
    return (r == 0) ? (1.f / 3.f) : ((r == 1) ? b : c);
}

// ---- static float4 component select (folds to a register at compile time) --
__device__ __forceinline__ float f4c(const float4& v, int c) {
    return (c == 0) ? v.x : ((c == 1) ? v.y : ((c == 2) ? v.z : v.w));
}

// ---- packed helpers ----
__device__ __forceinline__ f32x2 pkfma(f32x2 a, f32x2 b, f32x2 c) {
    return __builtin_elementwise_fma(a, b, c);
}
__device__ __forceinline__ f32x2 splat2(float v) { return (f32x2){v, v}; }

// ---- cross-lane xor via DPP (phase-2 recurrence; 16-lane-row local) ----
template<int CTRL> __device__ __forceinline__ float dppf(float x) {
    return __int_as_float(__builtin_amdgcn_mov_dpp(__float_as_int(x), CTRL, 0xF, 0xF, true));
}
template<int PL> __device__ __forceinline__ float mvf(float x) {
    if constexpr (PL == 1)      return dppf<0xB1>(x);    // quad_perm xor1
    else if constexpr (PL == 2) return dppf<0x4E>(x);    // quad_perm xor2
    else if constexpr (PL == 7) return dppf<0x141>(x);   // row_half_mirror = xor7
    else if constexpr (PL == 8) return dppf<0x128>(x);   // row_ror:8 = xor8
    else { static_assert(PL == 1 || PL == 2 || PL == 7 || PL == 8, "mask"); return x; }
}

// ---- full-state Ry in storage frame, PACKED {re,im}: mask m, functional F ----
template<int g>
__device__ __forceinline__ void gate_full2(f32x2 (&amp)[32], f32x2 cc, f32x2 ss) {
    constexpr int m = GMASK[g], F = FMASK[g];
    #pragma unroll
    for (int i = 0; i < 32; ++i) {
        if ((__builtin_popcount(i & F) & 1) == 0) {   // beta=0 member of pair
            const int j = i ^ m;                      // beta=1 (straddle assert)
            const f32x2 v0 = amp[i], v1 = amp[j];
            amp[i] = pkfma(cc, v0, -(ss * v1));       // c*v0 - s*v1 (re & im)
            amp[j] = pkfma(ss, v0,  cc * v1);         // s*v0 + c*v1
        }
    }
}

__global__ __launch_bounds__(1024, 4) void qrnn_fused(
    const float* __restrict__ x_seq, const float* __restrict__ w_rec,
    const float* __restrict__ w_out, float* __restrict__ out, int B) {

    __shared__ __align__(16) float4 xs4[32 * 33];     // staged x, padded rows
    __shared__ __align__(16) float A2s[18 * 28];      // contracted A, padded
    __shared__ float CgS[10], SgS[10];                // cos/sin(theta_g/2)
    __shared__ float F0c[5], F0s[5];                  // cos/sin(phi0_w/2)
    __shared__ __align__(8) f32x2 E1cs[32];           // interleaved {cos,sin}
    __shared__ float RC[16];                          // readout coefs
    __shared__ __align__(16) float Cm_pool[32 * 18 * 36];   // Cm; aliases Qs/P1s
    float* const Qs  = Cm_pool;                       // [486] eval results
    float* const P1s = Cm_pool + 512;                 // [486] C1 partials

    const int tloc = threadIdx.x;
    const int grp  = tloc >> 5;                       // 0..31: batch in block
    const int l    = tloc & 31;                       // 0..31: lane in batch
    const int k    = l & 15;                          // phase-2 slot
    const int b0   = blockIdx.x * 32;
    const int b    = b0 + grp;

    // ---- stage x: one (t, batch) pair per thread (1024 = 32t x 32b) ----
    {
        const int ts = tloc >> 5, lbs = tloc & 31;
        const int gidx = (ts * B + (b0 + lbs)) * 3;
        float4 v;
        v.x = x_seq[gidx]; v.y = x_seq[gidx + 1]; v.z = x_seq[gidx + 2]; v.w = 0.f;
        xs4[lbs * 33 + ts] = v;
    }

    // ---- stage A: all libm trig, distributed (depth ~2 calls) ----
    if (tloc < 10) {
        const float th = w_rec[(tloc / 5) * 15 + (tloc % 5) * 3 + 1];
        CgS[tloc] = cosf(0.5f * th);
        SgS[tloc] = sinf(0.5f * th);
    } else if (tloc >= 16 && tloc < 21) {             // per-qubit phi0/2
        const int w = tloc - 16;
        const float ph = 0.5f * w_rec[w * 3 + 0];
        F0c[w] = cosf(ph); F0s[w] = sinf(ph);
    } else if (tloc >= 64 && tloc < 96) {             // E1 = D_w0 * P1-frame D_phi1
        const int i = tloc - 64;
        const int j = pinv_rt(i, 1);
        float ang = 0.f;
        #pragma unroll
        for (int w = 0; w < 5; ++w) {
            ang += (((i >> (4 - w)) & 1) ? 0.5f : -0.5f) * w_rec[w * 3 + 2];
            ang += (((j >> (4 - w)) & 1) ? 0.5f : -0.5f) * w_rec[15 + w * 3 + 0];
        }
        E1cs[i] = (f32x2){cosf(ang), sinf(ang)};
    } else if (tloc >= 96 && tloc < 100) {            // readout gate coefs
        const int g = tloc - 96;                      // g = li*2 + w
        const int li = g >> 1, w = g & 1;
        const float phi = w_out[li * 6 + w * 3 + 0];
        const float the = w_out[li * 6 + w * 3 + 1];
        const float ome = w_out[li * 6 + w * 3 + 2];
        const float cs = cosf(0.5f * the), ss = sinf(0.5f * the);
        const float cp = cosf(0.5f * (phi + ome)), sp = sinf(0.5f * (phi + ome));
        const float cm = cosf(0.5f * (phi - ome)), sm = sinf(0.5f * (phi - ome));
        RC[g * 4 + 0] = cp * cs;
        RC[g * 4 + 1] = -sp * cs;
        RC[g * 4 + 2] = cm * ss;
        RC[g * 4 + 3] = sm * ss;
    }
    __syncthreads();

    // ---- stage B: per-thread full-state eval at exact combo angles ----
    if (tloc < 243) {
        const int dsel[5] = {tloc / 81, (tloc / 27) % 3, (tloc / 9) % 3,
                             (tloc / 3) % 3, tloc % 3};
        constexpr float S3v = 0.86602540378443865f;
        float Arw[5], Aiw[5], Brw[5], Biw[5];
        #pragma unroll
        for (int w = 0; w < 5; ++w) {
            const int d = dsel[w];
            const float fc = (d == 0) ? 1.f : 0.5f;
            const float fs = (d == 0) ? 0.f : ((d == 1) ? S3v : -S3v);
            const float c = CgS[w], s = SgS[w];
            const float t1 = fmaf(c, fc, -s * fs);   // c*fc - s*fs
            const float t2 = fmaf(c, fc,  s * fs);   // c*fc + s*fs
            const float t3 = fmaf(s, fc,  c * fs);   // s*fc + c*fs
            const float t4 = fmaf(c, fs, -s * fc);   // c*fs - s*fc
            Arw[w] =  F0c[w] * t1;  Aiw[w] = -F0s[w] * t2;
            Brw[w] =  F0c[w] * t3;  Biw[w] =  F0s[w] * t4;
        }
        f32x2 amp[32];
        amp[0] = (f32x2){Arw[0], Aiw[0]};
        amp[1] = (f32x2){Brw[0], Biw[0]};
        #pragma unroll
        for (int w = 1; w < 5; ++w) {
            const int n = 1 << w;
            #pragma unroll
            for (int m = n - 1; m >= 0; --m) {        // descending: in-place safe
                const float orr = amp[m].x, oii = amp[m].y;
                amp[2*m]   = (f32x2){fmaf(orr, Arw[w], -oii * Aiw[w]),
                                     fmaf(orr, Aiw[w],  oii * Arw[w])};
                amp[2*m+1] = (f32x2){fmaf(orr, Brw[w], -oii * Biw[w]),
                                     fmaf(orr, Biw[w],  oii * Brw[w])};
            }
        }
        // merged diagonal E1 (D_omega1 dropped: phase-blind)
        #pragma unroll
        for (int i = 0; i < 32; ++i) {
            const f32x2 e = E1cs[i];
            const f32x2 a = amp[i];
            amp[i] = (f32x2){a.x * e.x - a.y * e.y, a.x * e.y + a.y * e.x};
        }
        // layer 1 in storage frame, packed (GMASK/FMASK functionals)
        {
            const f32x2 c5 = splat2(CgS[5]), s5 = splat2(SgS[5]);
            const f32x2 c6 = splat2(CgS[6]), s6 = splat2(SgS[6]);
            const f32x2 c7 = splat2(CgS[7]), s7 = splat2(SgS[7]);
            const f32x2 c8 = splat2(CgS[8]), s8 = splat2(SgS[8]);
            const f32x2 c9 = splat2(CgS[9]), s9 = splat2(SgS[9]);
            gate_full2<5>(amp, c5, s5);
            gate_full2<6>(amp, c6, s6);
            gate_full2<7>(amp, c7, s7);
            gate_full2<8>(amp, c8, s8);
            gate_full2<9>(amp, c9, s9);
        }
        // expZ via SF3/SF4 sign functionals (R2-R8-validated)
        float q0 = 0.f, q1 = 0.f;
        #pragma unroll
        for (int i = 0; i < 32; ++i) {
            const f32x2 t = amp[i] * amp[i];          // v_pk_mul_f32
            const float p = t.x + t.y;
            q0 += (__builtin_popcount(i & SF3) & 1) ? -p : p;
            q1 += (__builtin_popcount(i & SF4) & 1) ? -p : p;
        }
        *(f32x2*)&Qs[tloc * 2] = (f32x2){q0, q1};
    }
    __syncthreads();

    // ---- stage C1: contract d3,d4 packed over j (Qs j-pairs adjacent) ----
    if (tloc < 243) {
        const int e = tloc;
        const int d012 = e / 9, pq = e % 9, pp = pq / 3, qq2 = pq % 3;
        f32x2 acc = (f32x2){0.f, 0.f};
        #pragma unroll
        for (int d3 = 0; d3 < 3; ++d3) {
            const float wp = Wsel(pp, d3);
            #pragma unroll
            for (int d4 = 0; d4 < 3; ++d4) {
                const float w = wp * Wsel(qq2, d4);
                const f32x2 qp = *(const f32x2*)&Qs[(d012 * 9 + d3 * 3 + d4) * 2];
                acc = pkfma(splat2(w), qp, acc);
            }
        }
        *(f32x2*)&P1s[(d012 * 9 + pq) * 2] = acc;
    }
    __syncthreads();

    // ---- stage C2: contract d0,d1,d2 packed over j -> A2s rows pq, 9+pq ----
    if (tloc < 243) {
        const int pq = tloc / 27, col = tloc % 27;
        const int a0 = col / 9, a1 = (col / 3) % 3, a2 = col % 3;
        f32x2 acc = (f32x2){0.f, 0.f};
        #pragma unroll
        for (int dd0 = 0; dd0 < 3; ++dd0) {
            const float w0 = Wsel(a0, dd0);
            #pragma unroll
            for (int dd1 = 0; dd1 < 3; ++dd1) {
                const float w01 = w0 * Wsel(a1, dd1);
                #pragma unroll
                for (int dd2 = 0; dd2 < 3; ++dd2) {
                    const float w = w01 * Wsel(a2, dd2);
                    const f32x2 pp = *(const f32x2*)
                        &P1s[((dd0 * 9 + dd1 * 3 + dd2) * 9 + pq) * 2];
                    acc = pkfma(splat2(w), pp, acc);
                }
            }
        }
        A2s[pq * 28 + col]       = acc.x;             // j=0 row
        A2s[(9 + pq) * 28 + col] = acc.y;             // j=1 row
    }
    if (tloc < 18) A2s[tloc * 28 + 27] = 0.f;
    __syncthreads();   // A2s ready; Qs/P1s dead -> Cm_pool reusable

    // ---- phase 1: one timestep per lane: C[t=l][row] = A-row . Xb ----
    constexpr float Kf = 0.15915494309189535f;   // 1/(2*pi)
    const f32x4* Ap = (const f32x4*)A2s;         // wave-uniform LDS broadcast
    f32x4 bA[7], bB[7];
    #pragma unroll
    for (int i = 0; i < 7; ++i) bA[i] = Ap[i];   // hoisted: lgkmcnt drains
    #pragma unroll
    for (int i = 0; i < 7; ++i) bB[i] = Ap[7 + i];   // under the Xb trig below

    f32x2 Xp[14];                                // packed even/odd basis pairs
    {
        float Xb[28];
        const float4 xv = xs4[grp * 33 + l];
        const float cx0 = __builtin_amdgcn_cosf(xv.x * Kf);
        const float sx0 = __builtin_amdgcn_cosf(fmaf(xv.x, Kf, -0.25f));
        const float cx1 = __builtin_amdgcn_cosf(xv.y * Kf);
        const float sx1 = __builtin_amdgcn_cosf(fmaf(xv.y, Kf, -0.25f));
        const float cx2 = __builtin_amdgcn_cosf(xv.z * Kf);
        const float sx2 = __builtin_amdgcn_cosf(fmaf(xv.z, Kf, -0.25f));
        Xb[0] = 1.f;  Xb[1] = cx2;       Xb[2] = sx2;
        Xb[3] = cx1;  Xb[4] = cx1 * cx2; Xb[5] = cx1 * sx2;
        Xb[6] = sx1;  Xb[7] = sx1 * cx2; Xb[8] = sx1 * sx2;
        #pragma unroll
        for (int i = 0; i < 9; ++i) { Xb[9 + i] = cx0 * Xb[i]; Xb[18 + i] = sx0 * Xb[i]; }
        Xb[27] = 0.f;
        #pragma unroll
        for (int j = 0; j < 14; ++j) Xp[j] = (f32x2){Xb[2 * j], Xb[2 * j + 1]};
    }
    {
        float* const Cmg = Cm_pool + grp * (18 * 36);
        #pragma unroll 1
        for (int r = 0; r < 18; r += 2) {
            {
                f32x2 A00 = {0.f,0.f}, A01 = {0.f,0.f};
                #pragma unroll
                for (int i = 0; i < 7; ++i) {
                    const f32x2 lo = __builtin_shufflevector(bA[i], bA[i], 0, 1);
                    const f32x2 hi = __builtin_shufflevector(bA[i], bA[i], 2, 3);
                    A00 = pkfma(lo, Xp[2*i],   A00);
                    A01 = pkfma(hi, Xp[2*i+1], A01);
                }
                const f32x2 S = A00 + A01;
                Cmg[r * 36 + l] = S.x + S.y;
                if (r < 16) {
                    #pragma unroll
                    for (int i = 0; i < 7; ++i) bA[i] = Ap[(r + 2) * 7 + i];
                }
            }
            {
                f32x2 A00 = {0.f,0.f}, A01 = {0.f,0.f};
                #pragma unroll
                for (int i = 0; i < 7; ++i) {
                    const f32x2 lo = __builtin_shufflevector(bB[i], bB[i], 0, 1);
                    const f32x2 hi = __builtin_shufflevector(bB[i], bB[i], 2, 3);
                    A00 = pkfma(lo, Xp[2*i],   A00);
                    A01 = pkfma(hi, Xp[2*i+1], A01);
                }
                const f32x2 S = A00 + A01;
                Cmg[(r + 1) * 36 + l] = S.x + S.y;
                if (r < 16) {
                    #pragma unroll
                    for (int i = 0; i < 7; ++i) bB[i] = Ap[(r + 3) * 7 + i];
                }
            }
        }
    }
    // Cm written/read within the same 32-lane group (same wave) -> no barrier

    // ---- phase 2: recurrence; slot k, duplicated across 16-lane halves ----
    const int jj = k >> 3;
    const int term = (k & 7) + 1;
    const int rowA = jj * 9 + term;
    const int rowB = (k == 8) ? 9 : 0;            // zero row eliminated (R15)
    const float cbf = (k == 0 || k == 8) ? 1.f : 0.f;
    const int p = term / 3, q = term % 3;
    const float4* CA4 = (const float4*)(Cm_pool + grp * (18 * 36) + rowA * 36);
    const float4* CB4 = (const float4*)(Cm_pool + grp * (18 * 36) + rowB * 36);

    float4 qa[8], qb[8];                          // 16 ds_read_b128
    #pragma unroll
    for (int i = 0; i < 8; ++i) { qa[i] = CA4[i]; qb[i] = CB4[i]; }
    #pragma unroll
    for (int i = 0; i < 8; ++i) {                 // CB := 0 unless k in {0,8}
        qb[i].x *= cbf; qb[i].y *= cbf; qb[i].z *= cbf; qb[i].w *= cbf;
    }

    const float Kfu = (p == 0) ? 0.f : Kf;       // cos(0)=1 for p==0 lanes
    const float bu  = (p == 2) ? -0.25f : 0.f;   // -0.25 rev = sin
    const float Kfv = (q == 0) ? 0.f : Kf;
    const float bv  = (q == 2) ? -0.25f : 0.f;

    float h0 = 0.f, h1 = 0.f;
    #pragma unroll
    for (int t = 0; t < 32; ++t) {
        const float u = __builtin_amdgcn_cosf(fmaf(h0, Kfu, bu));
        const float v = __builtin_amdgcn_cosf(fmaf(h1, Kfv, bv));
        float val = fmaf(f4c(qa[t >> 2], t & 3), u * v, f4c(qb[t >> 2], t & 3));
        val += mvf<1>(val);
        val += mvf<2>(val);
        val += mvf<7>(val);
        const float other = mvf<8>(val);
        h0 = (k & 8) ? other : val;
        h1 = (k & 8) ? val : other;
    }

    // ---- readout: precomputed coefs + HW h-trig (R10-validated) ----
    constexpr float K2 = 0.5f * 0.15915494309189535f;
    const float ch0 = __builtin_amdgcn_cosf(h0 * K2);
    const float sh0 = __builtin_amdgcn_cosf(fmaf(h0, K2, -0.25f));
    const float ch1 = __builtin_amdgcn_cosf(h1 * K2);
    const float sh1 = __builtin_amdgcn_cosf(fmaf(h1, K2, -0.25f));
    float vr0 = ch0 * ch1, vr1 = ch0 * sh1, vr2 = sh0 * ch1, vr3 = sh0 * sh1;
    float vi0 = 0.f, vi1 = 0.f, vi2 = 0.f, vi3 = 0.f;

    #pragma unroll
    for (int li = 0; li < 2; ++li) {
        #pragma unroll
        for (int w = 0; w < 2; ++w) {
            const int g = li * 2 + w;
            const float are = RC[g*4+0], aim = RC[g*4+1];
            const float bre = RC[g*4+2], bim = RC[g*4+3];
            #define AP2(r0, i0, r1, i1) do {                                  \
                float n0r = are*(r0) - aim*(i0) - bre*(r1) + bim*(i1);        \
                float n0i = are*(i0) + aim*(r0) - bre*(i1) - bim*(r1);        \
                float n1r = bre*(r0) + bim*(i0) + are*(r1) + aim*(i1);        \
                float n1i = bre*(i0) - bim*(r0) + are*(i1) - aim*(r1);        \
                r0 = n0r; i0 = n0i; r1 = n1r; i1 = n1i; } while (0)
            if (w == 0) { AP2(vr0, vi0, vr2, vi2); AP2(vr1, vi1, vr3, vi3); }
            else        { AP2(vr0, vi0, vr1, vi1); AP2(vr2, vi2, vr3, vi3); }
            #undef AP2
        }
        // CNOT(0,1) then CNOT(1,0): composed perm [0,2,3,1] (R1-verified)
        float tr1 = vr2, ti1 = vi2, tr2 = vr3, ti2 = vi3, tr3 = vr1, ti3 = vi1;
        vr1 = tr1; vi1 = ti1; vr2 = tr2; vi2 = ti2; vr3 = tr3; vi3 = ti3;
    }

    const float outv = (vr0 * vr0 + vi0 * vi0 + vr1 * vr1 + vi1 * vi1) -
                       (vr2 * vr2 + vi2 * vi2 + vr3 * vr3 + vi3 * vi3);
    if (l == 0) out[b] = outv;
}

extern "C" void kernel_launch(void* const* d_in, const int* in_sizes, int n_in,
                              void* d_out, int out_size, void* d_ws, size_t ws_size,
                              hipStream_t stream) {
    const float* x_seq = (const float*)d_in[0];
    const float* w_rec = (const float*)d_in[1];
    const float* w_out = (const float*)d_in[2];
    float* out = (float*)d_out;

    const int B = out_size;             // 8192 (T fixed at 32 by the bench)
    const int grid = B / 32;            // 256 blocks, 1/CU, 16 waves/CU

    hipLaunchKernelGGL(qrnn_fused, dim3(grid), dim3(1024), 0, stream,
                       x_seq, w_rec, w_out, out, B);
}

// Round 8
// 68.159 us; speedup vs baseline: 1.0913x; 1.0596x over previous
//
#include <hip/hip_runtime.h>
#include <math.h>

// ---------------------------------------------------------------------------
// FullyQuantumRNN, round 19: back to best geometry (R13/R16) + latency cuts.
// R17/R18 post-mortem: any geometry away from {512thr, 32 batch/block, 16
// lanes/batch, grid 256} regresses (setup redundancy or barrier/issue costs).
// R16 counters (VALUBusy 14%, Occ 18%, HBM~0) + consistent 4x payback per
// removed cycle => derated-clock, critical-path-cycle-bound kernel. R19 cuts
// exposed latency on the R16 base, geometry untouched:
//  - phase 1: 4-buffer (bA..bD) modulo schedule — each row-pair's 14
//    ds_read_b128 issued TWO compute-blocks (~120-240cy) before use, covering
//    the ~120-200cy LDS latency (was 1 block ~60-120cy -> ~2000cy exposed).
//  - stage A: all libm cosf/sinf -> HW v_cos revolution idiom (validated in
//    phases 1/2: cos(x)=hwcos(x*K), sin(x)=hwcos(x*K-0.25)). Removes ~30-instr
//    libm chains from the setup critical path that stage B waits on.
// Everything else verbatim R16 (packed stage B product tree, packed C1/C2,
// storage-frame GMASK/FMASK, folded-cos recurrence, f4c preload, zero-row
// elimination, 2-timesteps-per-lane phase 1).
// ---------------------------------------------------------------------------

using f32x2 = __attribute__((ext_vector_type(2))) float;
using f32x4 = __attribute__((ext_vector_type(4))) float;

// ---- compile-time permutation algebra (R1..R10-verified) ----
constexpr int cnot_ct(int idx, int c, int t) {
    return (idx & (1 << (4 - c))) ? (idx ^ (1 << (4 - t))) : idx;
}
constexpr int Pfwd_ct(int x, int r) {            // new[i] = old[Pfwd(i)]
    for (int w = 4; w >= 0; --w) x = cnot_ct(x, w, (w + r) % 5);
    return x;
}
constexpr int Pinv_ct(int x, int r) {
    for (int w = 0; w <= 4; ++w) x = cnot_ct(x, w, (w + r) % 5);
    return x;
}
static_assert(Pinv_ct(Pfwd_ct(13, 1), 1) == 13, "inv1");
static_assert(Pinv_ct(Pfwd_ct(22, 2), 2) == 22, "inv2");

// gate pair masks (storage-frame) and row-select functionals
constexpr int GMASK[10] = {16, 8, 4, 2, 1,
                           Pfwd_ct(16,1), Pfwd_ct(8,1), Pfwd_ct(4,1), Pfwd_ct(2,1), Pfwd_ct(1,1)};
constexpr int fmask_l1(int pb) {
    int f = 0;
    for (int b = 0; b < 5; ++b) if ((Pinv_ct(1 << b, 1) >> pb) & 1) f |= 1 << b;
    return f;
}
constexpr int FMASK[10] = {16, 8, 4, 2, 1,
                           fmask_l1(4), fmask_l1(3), fmask_l1(2), fmask_l1(1), fmask_l1(0)};
// expZ sign functionals on the storage index (final wires 3,4)
constexpr int cinv_ct(int x) { return Pinv_ct(Pinv_ct(x, 1), 2); }
constexpr int fmask_fin(int pb) {
    int f = 0;
    for (int b = 0; b < 5; ++b) if ((cinv_ct(1 << b) >> pb) & 1) f |= 1 << b;
    return f;
}
constexpr int SF3 = fmask_fin(1);
constexpr int SF4 = fmask_fin(0);

// each gate's pair must straddle its row-functional (one beta=0, one beta=1)
constexpr bool gates_straddle() {
    for (int g = 0; g < 10; ++g)
        if (!(__builtin_popcount(GMASK[g] & FMASK[g]) & 1)) return false;
    return true;
}
static_assert(gates_straddle(), "GMASK/FMASK straddle");

// phase-2 butterfly {1,2,7} spans 8-lane halves (R6-validated scheme)
constexpr unsigned span3_ct(int a, int b, int c) {
    unsigned m = 0;
    for (int i = 0; i < 8; ++i) {
        int v = ((i & 1) ? a : 0) ^ ((i & 2) ? b : 0) ^ ((i & 4) ? c : 0);
        m |= 1u << v;
    }
    return m;
}
static_assert(span3_ct(1, 2, 7) == 0xFFu, "butterfly {1,2,7} spans lanes 0..7");

__device__ __forceinline__ int pinv_rt(int x, int r) {
    #pragma unroll
    for (int w = 0; w < 5; ++w) {
        int cbit = 1 << (4 - w), tbit = 1 << (4 - ((w + r) % 5));
        if (x & cbit) x ^= tbit;
    }
    return x;
}

// ---- W = V^-1 rows, branchless ----
// W[0]={1/3,1/3,1/3}  W[1]={2/3,-1/3,-1/3}  W[2]={0,+s3,-s3}
__device__ __forceinline__ float Wsel(int r, int d) {
    float b, c;
    if (d == 0)      { b =  2.f / 3.f; c = 0.f; }
    else if (d == 1) { b = -1.f / 3.f; c =  0.57735026918962576f; }
    else             { b = -1.f / 3.f; c = -0.57735026918962576f; }
    return (r == 0) ? (1.f / 3.f) : ((r == 1) ? b : c);
}

// ---- static float4 component select (folds to a register at compile time) --
__device__ __forceinline__ float f4c(const float4& v, int c) {
    return (c == 0) ? v.x : ((c == 1) ? v.y : ((c == 2) ? v.z : v.w));
}

// ---- HW trig (revolution domain), validated in phases 1/2 ----
constexpr float KREV  = 0.15915494309189535f;        // 1/(2*pi)
__device__ __forceinline__ float hwcos_rad(float x)  {   // cos(x), x radians
    return __builtin_amdgcn_cosf(x * KREV);
}
__device__ __forceinline__ float hwsin_rad(float x)  {   // sin(x) = cos(x-pi/2)
    return __builtin_amdgcn_cosf(fmaf(x, KREV, -0.25f));
}

// ---- packed helpers ----
__device__ __forceinline__ f32x2 pkfma(f32x2 a, f32x2 b, f32x2 c) {
    return __builtin_elementwise_fma(a, b, c);
}
__device__ __forceinline__ f32x2 splat2(float v) { return (f32x2){v, v}; }

// ---- cross-lane xor via DPP (phase-2 recurrence; 16-lane-row local) ----
template<int CTRL> __device__ __forceinline__ float dppf(float x) {
    return __int_as_float(__builtin_amdgcn_mov_dpp(__float_as_int(x), CTRL, 0xF, 0xF, true));
}
template<int PL> __device__ __forceinline__ float mvf(float x) {
    if constexpr (PL == 1)      return dppf<0xB1>(x);    // quad_perm xor1
    else if constexpr (PL == 2) return dppf<0x4E>(x);    // quad_perm xor2
    else if constexpr (PL == 7) return dppf<0x141>(x);   // row_half_mirror = xor7
    else if constexpr (PL == 8) return dppf<0x128>(x);   // row_ror:8 = xor8
    else { static_assert(PL == 1 || PL == 2 || PL == 7 || PL == 8, "mask"); return x; }
}

// ---- full-state Ry in storage frame, PACKED {re,im}: mask m, functional F ----
template<int g>
__device__ __forceinline__ void gate_full2(f32x2 (&amp)[32], f32x2 cc, f32x2 ss) {
    constexpr int m = GMASK[g], F = FMASK[g];
    #pragma unroll
    for (int i = 0; i < 32; ++i) {
        if ((__builtin_popcount(i & F) & 1) == 0) {   // beta=0 member of pair
            const int j = i ^ m;                      // beta=1 (straddle assert)
            const f32x2 v0 = amp[i], v1 = amp[j];
            amp[i] = pkfma(cc, v0, -(ss * v1));       // c*v0 - s*v1 (re & im)
            amp[j] = pkfma(ss, v0,  cc * v1);         // s*v0 + c*v1
        }
    }
}

__global__ __launch_bounds__(512, 2) void qrnn_fused(
    const float* __restrict__ x_seq, const float* __restrict__ w_rec,
    const float* __restrict__ w_out, float* __restrict__ out, int B) {

    __shared__ __align__(16) float4 xs4[32 * 33];     // staged x, padded rows
    __shared__ __align__(16) float A2s[18 * 28];      // contracted A, padded
    __shared__ float CgS[10], SgS[10];                // cos/sin(theta_g/2)
    __shared__ float F0c[5], F0s[5];                  // cos/sin(phi0_w/2)
    __shared__ __align__(8) f32x2 E1cs[32];           // interleaved {cos,sin}
    __shared__ float RC[16];                          // readout coefs
    __shared__ __align__(16) float Cm_pool[32 * 18 * 36];   // Cm; aliases Qs/P1s
    float* const Qs  = Cm_pool;                       // [486] eval results
    float* const P1s = Cm_pool + 512;                 // [486] C1 partials

    const int tloc = threadIdx.x;
    const int grp  = tloc >> 4;                       // 0..31: batch in block
    const int k    = tloc & 15;
    const int b0   = blockIdx.x * 32;
    const int b    = b0 + grp;

    // ---- stage x (coalesced; consumed after barriers below) ----
    #pragma unroll
    for (int qq = 0; qq < 2; ++qq) {
        const int p = tloc + qq * 512;
        const int ts = p >> 5, lbs = p & 31;
        const int gidx = (ts * B + (b0 + lbs)) * 3;
        float4 v;
        v.x = x_seq[gidx]; v.y = x_seq[gidx + 1]; v.z = x_seq[gidx + 2]; v.w = 0.f;
        xs4[lbs * 33 + ts] = v;
    }

    // ---- stage A: all trig via HW v_cos (revolution idiom), distributed ----
    if (tloc < 10) {
        const float th = w_rec[(tloc / 5) * 15 + (tloc % 5) * 3 + 1];
        CgS[tloc] = hwcos_rad(0.5f * th);
        SgS[tloc] = hwsin_rad(0.5f * th);
    } else if (tloc >= 16 && tloc < 21) {             // per-qubit phi0/2
        const int w = tloc - 16;
        const float ph = 0.5f * w_rec[w * 3 + 0];
        F0c[w] = hwcos_rad(ph); F0s[w] = hwsin_rad(ph);
    } else if (tloc >= 64 && tloc < 96) {             // E1 = D_w0 * P1-frame D_phi1
        const int i = tloc - 64;
        const int j = pinv_rt(i, 1);
        float ang = 0.f;
        #pragma unroll
        for (int w = 0; w < 5; ++w) {
            ang += (((i >> (4 - w)) & 1) ? 0.5f : -0.5f) * w_rec[w * 3 + 2];
            ang += (((j >> (4 - w)) & 1) ? 0.5f : -0.5f) * w_rec[15 + w * 3 + 0];
        }
        E1cs[i] = (f32x2){hwcos_rad(ang), hwsin_rad(ang)};
    } else if (tloc >= 96 && tloc < 100) {            // readout gate coefs
        const int g = tloc - 96;                      // g = li*2 + w
        const int li = g >> 1, w = g & 1;
        const float phi = w_out[li * 6 + w * 3 + 0];
        const float the = w_out[li * 6 + w * 3 + 1];
        const float ome = w_out[li * 6 + w * 3 + 2];
        const float cs = hwcos_rad(0.5f * the), ss = hwsin_rad(0.5f * the);
        const float cp = hwcos_rad(0.5f * (phi + ome)), sp = hwsin_rad(0.5f * (phi + ome));
        const float cm = hwcos_rad(0.5f * (phi - ome)), sm = hwsin_rad(0.5f * (phi - ome));
        RC[g * 4 + 0] = cp * cs;
        RC[g * 4 + 1] = -sp * cs;
        RC[g * 4 + 2] = cm * ss;
        RC[g * 4 + 3] = sm * ss;
    }
    __syncthreads();

    // ---- stage B: per-thread full-state eval at exact combo angles ----
    if (tloc < 243) {
        const int dsel[5] = {tloc / 81, (tloc / 27) % 3, (tloc / 9) % 3,
                             (tloc / 3) % 3, tloc % 3};
        constexpr float S3v = 0.86602540378443865f;
        float Arw[5], Aiw[5], Brw[5], Biw[5];
        #pragma unroll
        for (int w = 0; w < 5; ++w) {
            const int d = dsel[w];
            const float fc = (d == 0) ? 1.f : 0.5f;
            const float fs = (d == 0) ? 0.f : ((d == 1) ? S3v : -S3v);
            const float c = CgS[w], s = SgS[w];
            const float t1 = fmaf(c, fc, -s * fs);   // c*fc - s*fs
            const float t2 = fmaf(c, fc,  s * fs);   // c*fc + s*fs
            const float t3 = fmaf(s, fc,  c * fs);   // s*fc + c*fs
            const float t4 = fmaf(c, fs, -s * fc);   // c*fs - s*fc
            Arw[w] =  F0c[w] * t1;  Aiw[w] = -F0s[w] * t2;
            Brw[w] =  F0c[w] * t3;  Biw[w] =  F0s[w] * t4;
        }
        f32x2 amp[32];
        amp[0] = (f32x2){Arw[0], Aiw[0]};
        amp[1] = (f32x2){Brw[0], Biw[0]};
        #pragma unroll
        for (int w = 1; w < 5; ++w) {
            const int n = 1 << w;
            #pragma unroll
            for (int m = n - 1; m >= 0; --m) {        // descending: in-place safe
                const float orr = amp[m].x, oii = amp[m].y;
                amp[2*m]   = (f32x2){fmaf(orr, Arw[w], -oii * Aiw[w]),
                                     fmaf(orr, Aiw[w],  oii * Arw[w])};
                amp[2*m+1] = (f32x2){fmaf(orr, Brw[w], -oii * Biw[w]),
                                     fmaf(orr, Biw[w],  oii * Brw[w])};
            }
        }
        // merged diagonal E1 (D_omega1 dropped: phase-blind)
        #pragma unroll
        for (int i = 0; i < 32; ++i) {
            const f32x2 e = E1cs[i];
            const f32x2 a = amp[i];
            amp[i] = (f32x2){a.x * e.x - a.y * e.y, a.x * e.y + a.y * e.x};
        }
        // layer 1 in storage frame, packed (GMASK/FMASK functionals)
        {
            const f32x2 c5 = splat2(CgS[5]), s5 = splat2(SgS[5]);
            const f32x2 c6 = splat2(CgS[6]), s6 = splat2(SgS[6]);
            const f32x2 c7 = splat2(CgS[7]), s7 = splat2(SgS[7]);
            const f32x2 c8 = splat2(CgS[8]), s8 = splat2(SgS[8]);
            const f32x2 c9 = splat2(CgS[9]), s9 = splat2(SgS[9]);
            gate_full2<5>(amp, c5, s5);
            gate_full2<6>(amp, c6, s6);
            gate_full2<7>(amp, c7, s7);
            gate_full2<8>(amp, c8, s8);
            gate_full2<9>(amp, c9, s9);
        }
        // expZ via SF3/SF4 sign functionals (R2-R8-validated)
        float q0 = 0.f, q1 = 0.f;
        #pragma unroll
        for (int i = 0; i < 32; ++i) {
            const f32x2 t = amp[i] * amp[i];          // v_pk_mul_f32
            const float p = t.x + t.y;
            q0 += (__builtin_popcount(i & SF3) & 1) ? -p : p;
            q1 += (__builtin_popcount(i & SF4) & 1) ? -p : p;
        }
        *(f32x2*)&Qs[tloc * 2] = (f32x2){q0, q1};
    }
    __syncthreads();

    // ---- stage C1: contract d3,d4 packed over j (Qs j-pairs adjacent) ----
    if (tloc < 243) {
        const int e = tloc;
        const int d012 = e / 9, pq = e % 9, pp = pq / 3, qq2 = pq % 3;
        f32x2 acc = (f32x2){0.f, 0.f};
        #pragma unroll
        for (int d3 = 0; d3 < 3; ++d3) {
            const float wp = Wsel(pp, d3);
            #pragma unroll
            for (int d4 = 0; d4 < 3; ++d4) {
                const float w = wp * Wsel(qq2, d4);
                const f32x2 qp = *(const f32x2*)&Qs[(d012 * 9 + d3 * 3 + d4) * 2];
                acc = pkfma(splat2(w), qp, acc);
            }
        }
        *(f32x2*)&P1s[(d012 * 9 + pq) * 2] = acc;
    }
    __syncthreads();

    // ---- stage C2: contract d0,d1,d2 packed over j -> A2s rows pq, 9+pq ----
    if (tloc < 243) {
        const int pq = tloc / 27, col = tloc % 27;
        const int a0 = col / 9, a1 = (col / 3) % 3, a2 = col % 3;
        f32x2 acc = (f32x2){0.f, 0.f};
        #pragma unroll
        for (int dd0 = 0; dd0 < 3; ++dd0) {
            const float w0 = Wsel(a0, dd0);
            #pragma unroll
            for (int dd1 = 0; dd1 < 3; ++dd1) {
                const float w01 = w0 * Wsel(a1, dd1);
                #pragma unroll
                for (int dd2 = 0; dd2 < 3; ++dd2) {
                    const float w = w01 * Wsel(a2, dd2);
                    const f32x2 pp = *(const f32x2*)
                        &P1s[((dd0 * 9 + dd1 * 3 + dd2) * 9 + pq) * 2];
                    acc = pkfma(splat2(w), pp, acc);
                }
            }
        }
        A2s[pq * 28 + col]       = acc.x;             // j=0 row
        A2s[(9 + pq) * 28 + col] = acc.y;             // j=1 row
    }
    if (tloc < 18) A2s[tloc * 28 + 27] = 0.f;
    __syncthreads();   // A2s ready; Qs/P1s dead -> Cm_pool reusable

    // ---- phase 1: C[t][row] = A-row . Xb(t); lane (grp,k) -> t = k, k+16 ----
    const f32x4* Ap = (const f32x4*)A2s;         // wave-uniform LDS broadcast
    float* const Cmg = Cm_pool + grp * (18 * 36);
    f32x4 bA[7], bB[7], bC[7], bD[7];            // 4-row modulo-schedule bufs

    #define P1LOAD(BUF, ridx) { _Pragma("unroll")                             \
        for (int i_ = 0; i_ < 7; ++i_) BUF[i_] = Ap[(ridx) * 7 + i_]; }
    #define P1COMP(BUF, ridx) {                                               \
        f32x2 A00={0.f,0.f}, A01={0.f,0.f}, A10={0.f,0.f}, A11={0.f,0.f};     \
        _Pragma("unroll")                                                     \
        for (int i_ = 0; i_ < 7; ++i_) {                                      \
            const f32x2 lo_ = __builtin_shufflevector(BUF[i_], BUF[i_], 0, 1);\
            const f32x2 hi_ = __builtin_shufflevector(BUF[i_], BUF[i_], 2, 3);\
            A00 = pkfma(lo_, Xp0[2*i_],   A00);                               \
            A01 = pkfma(hi_, Xp0[2*i_+1], A01);                               \
            A10 = pkfma(lo_, Xp1[2*i_],   A10);                               \
            A11 = pkfma(hi_, Xp1[2*i_+1], A11);                               \
        }                                                                     \
        const f32x2 S0_ = A00 + A01, S1_ = A10 + A11;                         \
        Cmg[(ridx) * 36 + k]      = S0_.x + S0_.y;                            \
        Cmg[(ridx) * 36 + k + 16] = S1_.x + S1_.y; }

    P1LOAD(bA, 0); P1LOAD(bB, 1);                // in flight under trig below

    f32x2 Xp0[14], Xp1[14];                      // packed even/odd basis pairs
    #pragma unroll
    for (int tt = 0; tt < 2; ++tt) {
        float Xb[28];
        const float4 xv = xs4[grp * 33 + k + 16 * tt];
        const float cx0 = __builtin_amdgcn_cosf(xv.x * KREV);
        const float sx0 = __builtin_amdgcn_cosf(fmaf(xv.x, KREV, -0.25f));
        const float cx1 = __builtin_amdgcn_cosf(xv.y * KREV);
        const float sx1 = __builtin_amdgcn_cosf(fmaf(xv.y, KREV, -0.25f));
        const float cx2 = __builtin_amdgcn_cosf(xv.z * KREV);
        const float sx2 = __builtin_amdgcn_cosf(fmaf(xv.z, KREV, -0.25f));
        Xb[0] = 1.f;  Xb[1] = cx2;       Xb[2] = sx2;
        Xb[3] = cx1;  Xb[4] = cx1 * cx2; Xb[5] = cx1 * sx2;
        Xb[6] = sx1;  Xb[7] = sx1 * cx2; Xb[8] = sx1 * sx2;
        #pragma unroll
        for (int i = 0; i < 9; ++i) { Xb[9 + i] = cx0 * Xb[i]; Xb[18 + i] = sx0 * Xb[i]; }
        Xb[27] = 0.f;
        #pragma unroll
        for (int j = 0; j < 14; ++j) {
            const f32x2 pr = (f32x2){Xb[2 * j], Xb[2 * j + 1]};
            if (tt == 0) Xp0[j] = pr; else Xp1[j] = pr;
        }
    }

    P1LOAD(bC, 2); P1LOAD(bD, 3);
    #pragma unroll 1
    for (int p = 0; p < 4; ++p) {
        const int r = 4 * p;
        P1COMP(bA, r);     P1COMP(bB, r + 1);
        P1LOAD(bA, r + 4); P1LOAD(bB, r + 5);    // 2 compute-blocks ahead
        P1COMP(bC, r + 2); P1COMP(bD, r + 3);
        if (p < 3) { P1LOAD(bC, r + 6); P1LOAD(bD, r + 7); }
    }
    P1COMP(bA, 16); P1COMP(bB, 17);
    #undef P1LOAD
    #undef P1COMP
    // Cm written/read within the same 16-lane group (same wave) -> no barrier

    // ---- phase 2: recurrence; lane k = coefficient slot (R12-validated) ----
    const int jj = k >> 3;
    const int term = (k & 7) + 1;
    const int rowA = jj * 9 + term;
    const int rowB = (k == 8) ? 9 : 0;            // zero row eliminated (R15)
    const float cbf = (k == 0 || k == 8) ? 1.f : 0.f;
    const int p = term / 3, q = term % 3;
    const float4* CA4 = (const float4*)(Cm_pool + grp * (18 * 36) + rowA * 36);
    const float4* CB4 = (const float4*)(Cm_pool + grp * (18 * 36) + rowB * 36);

    float4 qa[8], qb[8];                          // 16 ds_read_b128
    #pragma unroll
    for (int i = 0; i < 8; ++i) { qa[i] = CA4[i]; qb[i] = CB4[i]; }
    #pragma unroll
    for (int i = 0; i < 8; ++i) {                 // CB := 0 unless k in {0,8}
        qb[i].x *= cbf; qb[i].y *= cbf; qb[i].z *= cbf; qb[i].w *= cbf;
    }

    const float Kfu = (p == 0) ? 0.f : KREV;     // cos(0)=1 for p==0 lanes
    const float bu  = (p == 2) ? -0.25f : 0.f;   // -0.25 rev = sin
    const float Kfv = (q == 0) ? 0.f : KREV;
    const float bv  = (q == 2) ? -0.25f : 0.f;

    float h0 = 0.f, h1 = 0.f;
    #pragma unroll
    for (int t = 0; t < 32; ++t) {
        const float u = __builtin_amdgcn_cosf(fmaf(h0, Kfu, bu));
        const float v = __builtin_amdgcn_cosf(fmaf(h1, Kfv, bv));
        float val = fmaf(f4c(qa[t >> 2], t & 3), u * v, f4c(qb[t >> 2], t & 3));
        val += mvf<1>(val);
        val += mvf<2>(val);
        val += mvf<7>(val);
        const float other = mvf<8>(val);
        h0 = (k & 8) ? other : val;
        h1 = (k & 8) ? val : other;
    }

    // ---- readout: precomputed coefs + HW h-trig (R10-validated) ----
    constexpr float K2 = 0.5f * 0.15915494309189535f;
    const float ch0 = __builtin_amdgcn_cosf(h0 * K2);
    const float sh0 = __builtin_amdgcn_cosf(fmaf(h0, K2, -0.25f));
    const float ch1 = __builtin_amdgcn_cosf(h1 * K2);
    const float sh1 = __builtin_amdgcn_cosf(fmaf(h1, K2, -0.25f));
    float vr0 = ch0 * ch1, vr1 = ch0 * sh1, vr2 = sh0 * ch1, vr3 = sh0 * sh1;
    float vi0 = 0.f, vi1 = 0.f, vi2 = 0.f, vi3 = 0.f;

    #pragma unroll
    for (int li = 0; li < 2; ++li) {
        #pragma unroll
        for (int w = 0; w < 2; ++w) {
            const int g = li * 2 + w;
            const float are = RC[g*4+0], aim = RC[g*4+1];
            const float bre = RC[g*4+2], bim = RC[g*4+3];
            #define AP2(r0, i0, r1, i1) do {                                  \
                float n0r = are*(r0) - aim*(i0) - bre*(r1) + bim*(i1);        \
                float n0i = are*(i0) + aim*(r0) - bre*(i1) - bim*(r1);        \
                float n1r = bre*(r0) + bim*(i0) + are*(r1) + aim*(i1);        \
                float n1i = bre*(i0) - bim*(r0) + are*(i1) - aim*(r1);        \
                r0 = n0r; i0 = n0i; r1 = n1r; i1 = n1i; } while (0)
            if (w == 0) { AP2(vr0, vi0, vr2, vi2); AP2(vr1, vi1, vr3, vi3); }
            else        { AP2(vr0, vi0, vr1, vi1); AP2(vr2, vi2, vr3, vi3); }
            #undef AP2
        }
        // CNOT(0,1) then CNOT(1,0): composed perm [0,2,3,1] (R1-verified)
        float tr1 = vr2, ti1 = vi2, tr2 = vr3, ti2 = vi3, tr3 = vr1, ti3 = vi1;
        vr1 = tr1; vi1 = ti1; vr2 = tr2; vi2 = ti2; vr3 = tr3; vi3 = ti3;
    }

    const float outv = (vr0 * vr0 + vi0 * vi0 + vr1 * vr1 + vi1 * vi1) -
                       (vr2 * vr2 + vi2 * vi2 + vr3 * vr3 + vi3 * vi3);
    if (k == 0) out[b] = outv;
}

extern "C" void kernel_launch(void* const* d_in, const int* in_sizes, int n_in,
                              void* d_out, int out_size, void* d_ws, size_t ws_size,
                              hipStream_t stream) {
    const float* x_seq = (const float*)d_in[0];
    const float* w_rec = (const float*)d_in[1];
    const float* w_out = (const float*)d_in[2];
    float* out = (float*)d_out;

    const int B = out_size;             // 8192 (T fixed at 32 by the bench)
    const int grid = B / 32;            // 256 blocks, 1/CU (LDS ~102KB)

    hipLaunchKernelGGL(qrnn_fused, dim3(grid), dim3(512), 0, stream,
                       x_seq, w_rec, w_out, out, B);
}